// Round 6
// baseline (135.741 us; speedup 1.0000x reference)
//
#include <hip/hip_runtime.h>
#include <hip/hip_bf16.h>

// segment_sum: out[r] += edges[e] for receivers[e]==r.
// edges: [E=625000, D=128] f32, receivers: [E] i32, out: [N=50000, 128] f32.
//
// R1: f32-atomic scatter: MALL-atomic bound (1.25GB RMW, 1057us).
// R2: counting-sort + gather (266us). R3: custom zero kernel (249us).
// R4: vectorized aux + eid-shfl broadcast (165us).
// R5: pair-per-wave gather, rank-based atomic-free scatter, no nt on
//     edge loads (135us). Budget: aux ~35us, gather ~100us (~3.5 TB/s).
// R6 (this): branch-free gather. R5's loop split at the A/B boundary pushed
//     most rows through 2-row cleanup loops = 1 load in flight. Now: one flat
//     loop over the concatenated range, select-accumulate (cndmask 0/1 + fmac,
//     exact), 4 loads/body x unroll 2 = 8 loads (16 rows) in flight always,
//     zero branches inside a chunk, 32-bit edge addressing.

#define D_F4 32  // 128 floats = 32 float4 per row

typedef float f32x4 __attribute__((ext_vector_type(4)));

__global__ void zero_k(int4* __restrict__ p, int n_int4) {
    int i = blockIdx.x * blockDim.x + threadIdx.x;
    const int stride = gridDim.x * blockDim.x;
    const int4 z = make_int4(0, 0, 0, 0);
    for (; i < n_int4; i += stride) p[i] = z;
}

// counts[r]++ and remember each edge's arrival rank within its receiver.
__global__ void hist_rank_k(const int* __restrict__ recv, int* __restrict__ counts,
                            int* __restrict__ rank, int E) {
    const int E4 = E >> 2;
    const int i = blockIdx.x * blockDim.x + threadIdx.x;
    const int stride = gridDim.x * blockDim.x;
    for (int k = i; k < E4; k += stride) {
        const int4 r = ((const int4*)recv)[k];
        int4 p;
        p.x = atomicAdd(&counts[r.x], 1);
        p.y = atomicAdd(&counts[r.y], 1);
        p.z = atomicAdd(&counts[r.z], 1);
        p.w = atomicAdd(&counts[r.w], 1);
        ((int4*)rank)[k] = p;
    }
    if (i < (E & 3)) {
        const int e = (E4 << 2) + i;
        rank[e] = atomicAdd(&counts[recv[e]], 1);
    }
}

// One block, 1024 threads: vectorized chunked exclusive scan of counts -> offsets.
__global__ void scan_k(const int* __restrict__ counts, int* __restrict__ offsets, int N) {
    __shared__ int partials[1024];
    const int tid = threadIdx.x;
    int chunk = (N + 1023) >> 10;
    chunk = (chunk + 3) & ~3;
    const int lo = min(tid * chunk, N);
    const int hi = min(lo + chunk, N);

    int s = 0;
    int i = lo;
    for (; i + 4 <= hi; i += 4) {
        const int4 c4 = *(const int4*)(counts + i);
        s += c4.x + c4.y + c4.z + c4.w;
    }
    for (; i < hi; ++i) s += counts[i];
    partials[tid] = s;
    __syncthreads();
    for (int d = 1; d < 1024; d <<= 1) {
        const int v = (tid >= d) ? partials[tid - d] : 0;
        __syncthreads();
        partials[tid] += v;
        __syncthreads();
    }
    int run = (tid > 0) ? partials[tid - 1] : 0;
    i = lo;
    for (; i + 4 <= hi; i += 4) {
        const int4 c4 = *(const int4*)(counts + i);
        int4 o;
        o.x = run;
        o.y = run + c4.x;
        o.z = o.y + c4.y;
        o.w = o.z + c4.z;
        run = o.w + c4.w;
        *(int4*)(offsets + i) = o;
    }
    for (; i < hi; ++i) { offsets[i] = run; run += counts[i]; }
    if (tid == 1023) offsets[N] = partials[1023];
}

// atomic-free: pos = offsets[recv[e]] + rank[e]
__global__ void scatter_k(const int* __restrict__ recv, const int* __restrict__ rank,
                          const int* __restrict__ offsets, int* __restrict__ eids, int E) {
    const int E4 = E >> 2;
    const int i = blockIdx.x * blockDim.x + threadIdx.x;
    const int stride = gridDim.x * blockDim.x;
    for (int k = i; k < E4; k += stride) {
        const int4 r = ((const int4*)recv)[k];
        const int4 p = ((const int4*)rank)[k];
        const int e = k << 2;
        eids[offsets[r.x] + p.x] = e;
        eids[offsets[r.y] + p.y] = e + 1;
        eids[offsets[r.z] + p.z] = e + 2;
        eids[offsets[r.w] + p.w] = e + 3;
    }
    if (i < (E & 3)) {
        const int e = (E4 << 2) + i;
        eids[offsets[recv[e]] + rank[e]] = e;
    }
}

__device__ inline f32x4 xor32(f32x4 v) {
    f32x4 r;
    r.x = __shfl_xor(v.x, 32, 64);
    r.y = __shfl_xor(v.y, 32, 64);
    r.z = __shfl_xor(v.z, 32, 64);
    r.w = __shfl_xor(v.w, 32, 64);
    return r;
}

// One 64-lane wave per node pair (nA, nB); their eid ranges are adjacent, so
// [offsets[nA], offsets[nB+1]) is one contiguous stream. lane&31 = float4
// column, lane>>5 = which of 2 rows per load instruction. Single flat loop:
// every load unconditional, A/B boundary handled by select-accumulate
// (multiplier exactly 0.0/1.0 -> numerics identical to separate loops).
__global__ __launch_bounds__(256) void gather_k(const float* __restrict__ edges,
                                                const int* __restrict__ eids,
                                                const int* __restrict__ offsets,
                                                float* __restrict__ out, int N) {
    const int wave = (blockIdx.x * blockDim.x + threadIdx.x) >> 6;
    const int lane = threadIdx.x & 63;
    const int c = lane & 31;
    const int h = lane >> 5;
    const int nA = wave << 1;
    if (nA >= N) return;
    const int nB = nA | 1;
    const int loA = offsets[nA];
    const int loB = offsets[nA + 1];                  // == hiA
    const int hiB = (nB < N) ? offsets[nB + 1] : loB;

    f32x4 a0 = {0,0,0,0}, a1 = {0,0,0,0}, a2 = {0,0,0,0}, a3 = {0,0,0,0};
    f32x4 b0 = {0,0,0,0}, b1 = {0,0,0,0}, b2 = {0,0,0,0}, b3 = {0,0,0,0};

    const unsigned cbase = (unsigned)c << 2;          // float offset within row

    for (int base = loA; base < hiB; base += 64) {
        const int cnt = min(64, hiB - base);
        const int splitL = min(max(loB - base, 0), cnt);   // local A/B boundary
        const int myE = eids[min(base + lane, hiB - 1)];   // coalesced 64 eids
        const int last = cnt - 1;
#pragma unroll 2
        for (int jj = 0; jj < cnt; jj += 8) {
            const int j0 = jj + 0 + h, j1 = jj + 2 + h, j2 = jj + 4 + h, j3 = jj + 6 + h;
            const int e0 = __shfl(myE, min(j0, last), 64);
            const int e1 = __shfl(myE, min(j1, last), 64);
            const int e2 = __shfl(myE, min(j2, last), 64);
            const int e3 = __shfl(myE, min(j3, last), 64);
            const f32x4 v0 = *(const f32x4*)(edges + (((unsigned)e0 << 7) + cbase));
            const f32x4 v1 = *(const f32x4*)(edges + (((unsigned)e1 << 7) + cbase));
            const f32x4 v2 = *(const f32x4*)(edges + (((unsigned)e2 << 7) + cbase));
            const f32x4 v3 = *(const f32x4*)(edges + (((unsigned)e3 << 7) + cbase));
            const float sA0 = (j0 < splitL) ? 1.f : 0.f;
            const float sA1 = (j1 < splitL) ? 1.f : 0.f;
            const float sA2 = (j2 < splitL) ? 1.f : 0.f;
            const float sA3 = (j3 < splitL) ? 1.f : 0.f;
            const float sB0 = (j0 >= splitL && j0 < cnt) ? 1.f : 0.f;
            const float sB1 = (j1 >= splitL && j1 < cnt) ? 1.f : 0.f;
            const float sB2 = (j2 >= splitL && j2 < cnt) ? 1.f : 0.f;
            const float sB3 = (j3 >= splitL && j3 < cnt) ? 1.f : 0.f;
            a0 += v0 * sA0; b0 += v0 * sB0;
            a1 += v1 * sA1; b1 += v1 * sB1;
            a2 += v2 * sA2; b2 += v2 * sB2;
            a3 += v3 * sA3; b3 += v3 * sB3;
        }
    }
    a0 += a1; a2 += a3; a0 += a2;
    b0 += b1; b2 += b3; b0 += b2;
    a0 += xor32(a0);   // both halves now hold full node-A sum
    b0 += xor32(b0);
    const int row = h ? nB : nA;
    const f32x4 r = h ? b0 : a0;
    if (row < N)
        __builtin_nontemporal_store(r, (f32x4*)out + (long long)row * D_F4 + c);
}

// -------- fallback (atomic version) if ws_size is too small --------
__global__ void seg_sum_atomic(const float4* __restrict__ edges,
                               const int* __restrict__ recv,
                               float* __restrict__ out, int n_edges) {
    const long long total = (long long)n_edges * D_F4;
    long long idx = (long long)blockIdx.x * blockDim.x + threadIdx.x;
    const long long stride = (long long)gridDim.x * blockDim.x;
    for (; idx < total; idx += stride) {
        const int e = (int)(idx >> 5);
        const int c = (int)(idx & 31);
        const float4 v = edges[(long long)e * D_F4 + c];
        const int r = recv[e];
        float* o = out + (long long)r * 128 + c * 4;
        atomicAdd(o + 0, v.x);
        atomicAdd(o + 1, v.y);
        atomicAdd(o + 2, v.z);
        atomicAdd(o + 3, v.w);
    }
}

extern "C" void kernel_launch(void* const* d_in, const int* in_sizes, int n_in,
                              void* d_out, int out_size, void* d_ws, size_t ws_size,
                              hipStream_t stream) {
    const float* edges = (const float*)d_in[0];
    const int* recv = (const int*)d_in[1];
    float* out = (float*)d_out;

    const int E = in_sizes[1];            // 625000
    const int N = out_size / 128;         // 50000 nodes

    // workspace (ints), 16B-aligned segments:
    //   counts[countsPad] | offsets[offsPad] | rank[E] | eids[E]
    const int countsPad = (N + 3) & ~3;
    const int offsPad = ((N + 1) + 3) & ~3;
    const size_t need = (size_t)(countsPad + offsPad + 2 * (size_t)E) * sizeof(int);
    if (ws_size < need) {
        zero_k<<<256, 256, 0, stream>>>((int4*)d_out, out_size / 4);
        const long long total = (long long)E * D_F4;
        int grid = (int)((total + 255) / 256);
        if (grid > 4096) grid = 4096;
        seg_sum_atomic<<<grid, 256, 0, stream>>>((const float4*)edges, recv, out, E);
        return;
    }

    int* counts = (int*)d_ws;
    int* offsets = counts + countsPad;
    int* rank = offsets + offsPad;
    int* eids = rank + E;

    const int block = 256;

    zero_k<<<64, block, 0, stream>>>((int4*)counts, countsPad / 4);

    const int E4 = E >> 2;
    const int gridE4 = (E4 + block - 1) / block;

    hist_rank_k<<<gridE4, block, 0, stream>>>(recv, counts, rank, E);
    scan_k<<<1, 1024, 0, stream>>>(counts, offsets, N);
    scatter_k<<<gridE4, block, 0, stream>>>(recv, rank, offsets, eids, E);

    const int nPairs = (N + 1) / 2;                    // one 64-lane wave per pair
    const int gridN = (nPairs * 64 + block - 1) / block;
    gather_k<<<gridN, block, 0, stream>>>(edges, eids, offsets, out, N);
}